// Round 8
// baseline (447.331 us; speedup 1.0000x reference)
//
#include <hip/hip_runtime.h>

typedef unsigned short ushort_t;
typedef __attribute__((ext_vector_type(8))) short short8;
typedef __attribute__((ext_vector_type(4))) float floatx4;
typedef __attribute__((ext_vector_type(2))) float floatx2;

#define N_NODES 8192
#define N_EDGES 262144
#define D_FEAT 512
#define NHID 32
#define LATENT 16

#define ADJ_OFF 0
#define FEAT_OFF (8192*8192)
#define Z_OFF (8192*8192 + 8192*512)

static __device__ __forceinline__ ushort_t f2bf(float f) {
    unsigned int u = __float_as_uint(f);
    unsigned int r = u + 0x7fffu + ((u >> 16) & 1u);  // RNE
    return (ushort_t)(r >> 16);
}

// sigmoid via native exp2 + rcp (no IEEE div sequence); |err| ~1e-7
static __device__ __forceinline__ float fsig(float x) {
    float e = __builtin_amdgcn_exp2f(x * -1.44269504f);
    return __builtin_amdgcn_rcpf(1.f + e);
}

// ---------------------------------------------------------------------------
// K_enc: xwg = feat @ Wg1 ; he1 = relu(feat @ We1 + be1) ; zx = relu(he1@We2+be2)
// 512 blocks x 16 nodes (2 blocks/CU). thread = 1 node x 4 cols of 64-concat.
// Also zeroes counts[] for k_hist (which runs after).
// ---------------------------------------------------------------------------
__global__ __launch_bounds__(256) void k_enc(const float* __restrict__ feat,
                                             const float* __restrict__ Wg1,
                                             const float* __restrict__ We1,
                                             const float* __restrict__ be1,
                                             const float* __restrict__ We2,
                                             const float* __restrict__ be2,
                                             float* __restrict__ xwg,
                                             float* __restrict__ zxf,
                                             int* __restrict__ counts) {
    __shared__ float WL[32][64];   // 8 KB   [k][c]
    __shared__ float FL[16][36];   // 2.3 KB [n][k]
    __shared__ float HE[16][33];
    int tid = threadIdx.x;
    int gid = blockIdx.x * 256 + tid;
    if (gid < N_NODES) counts[gid] = 0;

    int n = tid >> 4;              // 0..15 node
    int cr = tid & 15;             // col quad (4 cols)
    int m0 = blockIdx.x * 16;
    float acc[4] = {};

    for (int kt = 0; kt < 16; kt++) {
        __syncthreads();
        // stage WL: 32 k x 64 c
        {
            int i = tid;
            #pragma unroll
            for (int j = 0; j < 8; j++, i += 256) {
                int k = i >> 6, c = i & 63;
                int kg = kt * 32 + k;
                WL[k][c] = (c < 32) ? Wg1[kg * 32 + c] : We1[kg * 32 + (c - 32)];
            }
        }
        // stage FL: 16 n x 32 k (128 threads x float4)
        if (tid < 128) {
            int nn = tid >> 3, q = tid & 7;
            float4 v = *(const float4*)(feat + (m0 + nn) * 512 + kt * 32 + q * 4);
            FL[nn][q * 4 + 0] = v.x; FL[nn][q * 4 + 1] = v.y;
            FL[nn][q * 4 + 2] = v.z; FL[nn][q * 4 + 3] = v.w;
        }
        __syncthreads();
        #pragma unroll 4
        for (int k = 0; k < 32; k++) {
            float4 w = *(const float4*)&WL[k][cr * 4];
            float f0 = FL[n][k];
            acc[0] += f0 * w.x; acc[1] += f0 * w.y;
            acc[2] += f0 * w.z; acc[3] += f0 * w.w;
        }
    }
    int cg = cr * 4;
    if (cg < 32) {
        float4 v = make_float4(acc[0], acc[1], acc[2], acc[3]);
        *(float4*)(xwg + (m0 + n) * 32 + cg) = v;
    } else {
        int hc = cg - 32;
        #pragma unroll
        for (int t = 0; t < 4; t++) {
            float v = acc[t] + be1[hc + t];
            HE[n][hc + t] = v > 0.f ? v : 0.f;
        }
    }
    __syncthreads();
    // zx = relu(he1 @ We2 + be2): 16 n x 16 j, one value per thread
    {
        int j = cr;
        float s = be2[j];
        #pragma unroll 8
        for (int cc = 0; cc < 32; cc++) s += HE[n][cc] * We2[cc * 16 + j];
        zxf[(m0 + n) * 16 + j] = s > 0.f ? s : 0.f;
    }
}

// ---------------------------------------------------------------------------
// CSR build: histogram, scan, scatter (counting sort by dst)
// ---------------------------------------------------------------------------
__global__ __launch_bounds__(256) void k_hist(const int* __restrict__ edst, int* __restrict__ counts) {
    int e = blockIdx.x * 256 + threadIdx.x;
    atomicAdd(&counts[edst[e]], 1);
}

__global__ __launch_bounds__(1024) void k_scan(const int* __restrict__ counts,
                                               int* __restrict__ offs, int* __restrict__ cursor) {
    __shared__ int sdata[1024];
    int t = threadIdx.x;
    int base = t * 8;
    int c[8], local[8];
    int s = 0;
    #pragma unroll
    for (int j = 0; j < 8; j++) { c[j] = counts[base + j]; }
    #pragma unroll
    for (int j = 0; j < 8; j++) { local[j] = s; s += c[j]; }
    sdata[t] = s;
    __syncthreads();
    for (int off = 1; off < 1024; off <<= 1) {
        int v = sdata[t];
        int add = (t >= off) ? sdata[t - off] : 0;
        __syncthreads();
        sdata[t] = v + add;
        __syncthreads();
    }
    int excl = (t == 0) ? 0 : sdata[t - 1];
    #pragma unroll
    for (int j = 0; j < 8; j++) {
        int o = excl + local[j];
        offs[base + j] = o;
        cursor[base + j] = o;
    }
}

__global__ __launch_bounds__(256) void k_scatter(const int* __restrict__ esrc,
                                                 const int* __restrict__ edst,
                                                 const float* __restrict__ ew,
                                                 int* __restrict__ cursor,
                                                 int2* __restrict__ sedge) {
    int e = blockIdx.x * 256 + threadIdx.x;
    int d = edst[e];
    int pos = atomicAdd(&cursor[d], 1);
    sedge[pos] = make_int2(esrc[e], __float_as_int(ew[e]));
}

// ---------------------------------------------------------------------------
// K_agg1: h = relu(segsum(xwg[src]*w) + bg1); hw2 = h @ Wg2
// block = 8 nodes x 32 lanes; unroll-4 batched gather
// ---------------------------------------------------------------------------
__global__ __launch_bounds__(256) void k_agg1(const float* __restrict__ xwg,
                                              const int* __restrict__ offs,
                                              const int* __restrict__ counts,
                                              const int2* __restrict__ sedge,
                                              const float* __restrict__ bg1,
                                              const float* __restrict__ Wg2,
                                              float* __restrict__ hw2) {
    __shared__ float hsh[8][33];
    int ln = threadIdx.x >> 5, c = threadIdx.x & 31;
    int n = blockIdx.x * 8 + ln;
    int st = offs[n], en = st + counts[n];
    float acc = 0.f;
    int i = st;
    for (; i + 4 <= en; i += 4) {
        int2 e0 = sedge[i], e1 = sedge[i + 1], e2 = sedge[i + 2], e3 = sedge[i + 3];
        float s0 = __int_as_float(e0.y) * xwg[e0.x * 32 + c];
        float s1 = __int_as_float(e1.y) * xwg[e1.x * 32 + c];
        float s2 = __int_as_float(e2.y) * xwg[e2.x * 32 + c];
        float s3 = __int_as_float(e3.y) * xwg[e3.x * 32 + c];
        acc += (s0 + s1) + (s2 + s3);
    }
    for (; i < en; i++) {
        int2 e = sedge[i];
        acc += __int_as_float(e.y) * xwg[e.x * 32 + c];
    }
    float h = acc + bg1[c];
    hsh[ln][c] = h > 0.f ? h : 0.f;
    __syncthreads();
    if (threadIdx.x < 128) {
        int l2 = threadIdx.x >> 4, j = threadIdx.x & 15;
        float s2 = 0.f;
        #pragma unroll 8
        for (int cc = 0; cc < 32; cc++) s2 += hsh[l2][cc] * Wg2[cc * 16 + j];
        hw2[(blockIdx.x * 8 + l2) * 16 + j] = s2;
    }
}

// ---------------------------------------------------------------------------
// K_agg2: za = relu(segsum(hw2[src]*w) + bg2); z output (f32) + zbf (bf16)
// block = 16 nodes x 16 lanes
// ---------------------------------------------------------------------------
__global__ __launch_bounds__(256) void k_agg2(const float* __restrict__ hw2,
                                              const int* __restrict__ offs,
                                              const int* __restrict__ counts,
                                              const int2* __restrict__ sedge,
                                              const float* __restrict__ bg2,
                                              const float* __restrict__ zxf,
                                              ushort_t* __restrict__ zbf,
                                              float* __restrict__ zout) {
    int ln = threadIdx.x >> 4, c = threadIdx.x & 15;
    int n = blockIdx.x * 16 + ln;
    int st = offs[n], en = st + counts[n];
    float acc = 0.f;
    int i = st;
    for (; i + 4 <= en; i += 4) {
        int2 e0 = sedge[i], e1 = sedge[i + 1], e2 = sedge[i + 2], e3 = sedge[i + 3];
        float s0 = __int_as_float(e0.y) * hw2[e0.x * 16 + c];
        float s1 = __int_as_float(e1.y) * hw2[e1.x * 16 + c];
        float s2 = __int_as_float(e2.y) * hw2[e2.x * 16 + c];
        float s3 = __int_as_float(e3.y) * hw2[e3.x * 16 + c];
        acc += (s0 + s1) + (s2 + s3);
    }
    for (; i < en; i++) {
        int2 e = sedge[i];
        acc += __int_as_float(e.y) * hw2[e.x * 16 + c];
    }
    float za = acc + bg2[c];
    za = za > 0.f ? za : 0.f;
    float zx = zxf[n * 16 + c];
    zout[n * 32 + c] = za;
    zout[n * 32 + 16 + c] = zx;
    zbf[n * 32 + c] = f2bf(za);
    zbf[n * 32 + 16 + c] = f2bf(zx);
}

// ---------------------------------------------------------------------------
// K_out: blocks [0,2048): adj = sigmoid(z z^T) via bf16 MFMA + fast sigmoid;
//        blocks [2048,2560): feat_recon = relu(relu(zx@Wd1+bd1)@Wd2+bd2).
// R8: plain (non-nontemporal) stores — the rocclr fill kernel proves plain
// stores reach 6.5 TB/s; nt was the single变量 under test.
// ---------------------------------------------------------------------------
__global__ __launch_bounds__(256) void k_out(const ushort_t* __restrict__ zbf,
                                             const float* __restrict__ zxf,
                                             const float* __restrict__ Wd1,
                                             const float* __restrict__ bd1,
                                             const float* __restrict__ Wd2,
                                             const float* __restrict__ bd2,
                                             float* __restrict__ out) {
    __shared__ float ZL[16][17];
    __shared__ float HT[16][33];
    int tid = threadIdx.x;
    if (blockIdx.x < 2048) {
        float* adj = out + ADJ_OFF;
        int l = tid & 63;
        int wv = tid >> 6;
        int strip = blockIdx.x & 15;
        int rt = (blockIdx.x >> 4) * 4 + wv;
        int q = l >> 4, cl = l & 15;
        int m0 = rt * 16, c0 = strip * 512;
        short8 a = *(const short8*)(zbf + (m0 + cl) * 32 + q * 8);
        for (int g = 0; g < 8; g++) {
            int cb = c0 + g * 64;
            short8 b0 = *(const short8*)(zbf + (cb + 4 * cl + 0) * 32 + q * 8);
            short8 b1 = *(const short8*)(zbf + (cb + 4 * cl + 1) * 32 + q * 8);
            short8 b2 = *(const short8*)(zbf + (cb + 4 * cl + 2) * 32 + q * 8);
            short8 b3 = *(const short8*)(zbf + (cb + 4 * cl + 3) * 32 + q * 8);
            floatx4 zv = {0, 0, 0, 0};
            floatx4 a0 = __builtin_amdgcn_mfma_f32_16x16x32_bf16(a, b0, zv, 0, 0, 0);
            floatx4 a1 = __builtin_amdgcn_mfma_f32_16x16x32_bf16(a, b1, zv, 0, 0, 0);
            floatx4 a2 = __builtin_amdgcn_mfma_f32_16x16x32_bf16(a, b2, zv, 0, 0, 0);
            floatx4 a3 = __builtin_amdgcn_mfma_f32_16x16x32_bf16(a, b3, zv, 0, 0, 0);
            #pragma unroll
            for (int r = 0; r < 4; r++) {
                floatx4 v;
                v.x = fsig(a0[r]);
                v.y = fsig(a1[r]);
                v.z = fsig(a2[r]);
                v.w = fsig(a3[r]);
                int row = m0 + q * 4 + r;
                *(floatx4*)(adj + (size_t)row * 8192 + cb + 4 * cl) = v;
            }
        }
    } else {
        float* outF = out + FEAT_OFF;
        int m0 = (blockIdx.x - 2048) * 16;
        {
            int n = tid >> 4, k = tid & 15;
            ZL[n][k] = zxf[(m0 + n) * 16 + k];
        }
        __syncthreads();
        {
            int o = tid * 2;
            int n = o >> 5, c = o & 31;
            float s0 = bd1[c], s1 = bd1[c + 1];
            #pragma unroll
            for (int k = 0; k < 16; k++) {
                float z = ZL[n][k];
                s0 += z * Wd1[k * 32 + c];
                s1 += z * Wd1[k * 32 + c + 1];
            }
            HT[n][c] = s0 > 0.f ? s0 : 0.f;
            HT[n][c + 1] = s1 > 0.f ? s1 : 0.f;
        }
        __syncthreads();
        int c2 = tid * 2;
        floatx2 acc[16];
        #pragma unroll
        for (int n = 0; n < 16; n++) acc[n] = (floatx2){0.f, 0.f};
        for (int k = 0; k < 32; k++) {
            float2 w = *(const float2*)(Wd2 + k * 512 + c2);
            #pragma unroll
            for (int n = 0; n < 16; n++) {
                float t = HT[n][k];
                acc[n].x += t * w.x;
                acc[n].y += t * w.y;
            }
        }
        float b0 = bd2[c2], b1 = bd2[c2 + 1];
        #pragma unroll
        for (int n = 0; n < 16; n++) {
            float s0 = acc[n].x + b0, s1 = acc[n].y + b1;
            s0 = s0 > 0.f ? s0 : 0.f;
            s1 = s1 > 0.f ? s1 : 0.f;
            floatx2 pk = {s0, s1};
            *(floatx2*)(outF + (size_t)(m0 + n) * 512 + c2) = pk;
        }
    }
}

// ---------------------------------------------------------------------------
extern "C" void kernel_launch(void* const* d_in, const int* in_sizes, int n_in,
                              void* d_out, int out_size, void* d_ws, size_t ws_size,
                              hipStream_t stream) {
    const float* feat = (const float*)d_in[0];
    const int* esrc = (const int*)d_in[1];
    const int* edst = (const int*)d_in[2];
    const float* ew = (const float*)d_in[3];
    const float* Wg1 = (const float*)d_in[4];
    const float* bg1 = (const float*)d_in[5];
    const float* Wg2 = (const float*)d_in[6];
    const float* bg2 = (const float*)d_in[7];
    const float* We1 = (const float*)d_in[8];
    const float* be1 = (const float*)d_in[9];
    const float* We2 = (const float*)d_in[10];
    const float* be2 = (const float*)d_in[11];
    const float* Wd1 = (const float*)d_in[12];
    const float* bd1 = (const float*)d_in[13];
    const float* Wd2 = (const float*)d_in[14];
    const float* bd2 = (const float*)d_in[15];
    float* out = (float*)d_out;

    char* ws = (char*)d_ws;
    float* xwg      = (float*)(ws + 0);            // 1 MB
    float* zxf      = (float*)(ws + 1048576);      // 512 KB
    float* hw2      = (float*)(ws + 1572864);      // 512 KB
    ushort_t* zbf   = (ushort_t*)(ws + 2097152);   // 512 KB
    int* counts     = (int*)(ws + 2621440);        // 32 KB
    int* offs       = (int*)(ws + 2654208);        // 32 KB
    int* cursor     = (int*)(ws + 2686976);        // 32 KB
    int2* sedge     = (int2*)(ws + 2719744);       // 2 MB

    k_enc<<<N_NODES / 16, 256, 0, stream>>>(feat, Wg1, We1, be1, We2, be2,
                                            xwg, zxf, counts);
    k_hist<<<N_EDGES / 256, 256, 0, stream>>>(edst, counts);
    k_scan<<<1, 1024, 0, stream>>>(counts, offs, cursor);
    k_scatter<<<N_EDGES / 256, 256, 0, stream>>>(esrc, edst, ew, cursor, sedge);
    k_agg1<<<N_NODES / 8, 256, 0, stream>>>(xwg, offs, counts, sedge, bg1, Wg2, hw2);
    k_agg2<<<N_NODES / 16, 256, 0, stream>>>(hw2, offs, counts, sedge, bg2, zxf,
                                             zbf, out + Z_OFF);
    k_out<<<2048 + 512, 256, 0, stream>>>(zbf, zxf, Wd1, bd1, Wd2, bd2, out);
}

// Round 9
// 438.415 us; speedup vs baseline: 1.0203x; 1.0203x over previous
//
#include <hip/hip_runtime.h>

typedef unsigned short ushort_t;
typedef __attribute__((ext_vector_type(8))) short short8;
typedef __attribute__((ext_vector_type(4))) float floatx4;
typedef __attribute__((ext_vector_type(2))) float floatx2;

#define N_NODES 8192
#define N_EDGES 262144
#define D_FEAT 512
#define NHID 32
#define LATENT 16

#define ADJ_OFF 0
#define FEAT_OFF (8192*8192)
#define Z_OFF (8192*8192 + 8192*512)

static __device__ __forceinline__ ushort_t f2bf(float f) {
    unsigned int u = __float_as_uint(f);
    unsigned int r = u + 0x7fffu + ((u >> 16) & 1u);  // RNE
    return (ushort_t)(r >> 16);
}

// sigmoid via native exp2 + rcp; |err| ~1e-7
static __device__ __forceinline__ float fsig(float x) {
    float e = __builtin_amdgcn_exp2f(x * -1.44269504f);
    return __builtin_amdgcn_rcpf(1.f + e);
}

// ---------------------------------------------------------------------------
// K_enc: xwg = feat @ Wg1 ; he1 = relu(feat @ We1 + be1) ; zx = relu(he1@We2+be2)
// 512 blocks x 16 nodes. Also zeroes counts[] for k_hist.
// ---------------------------------------------------------------------------
__global__ __launch_bounds__(256) void k_enc(const float* __restrict__ feat,
                                             const float* __restrict__ Wg1,
                                             const float* __restrict__ We1,
                                             const float* __restrict__ be1,
                                             const float* __restrict__ We2,
                                             const float* __restrict__ be2,
                                             float* __restrict__ xwg,
                                             float* __restrict__ zxf,
                                             int* __restrict__ counts) {
    __shared__ float WL[32][64];
    __shared__ float FL[16][36];
    __shared__ float HE[16][33];
    int tid = threadIdx.x;
    int gid = blockIdx.x * 256 + tid;
    if (gid < N_NODES) counts[gid] = 0;

    int n = tid >> 4;
    int cr = tid & 15;
    int m0 = blockIdx.x * 16;
    float acc[4] = {};

    for (int kt = 0; kt < 16; kt++) {
        __syncthreads();
        {
            int i = tid;
            #pragma unroll
            for (int j = 0; j < 8; j++, i += 256) {
                int k = i >> 6, c = i & 63;
                int kg = kt * 32 + k;
                WL[k][c] = (c < 32) ? Wg1[kg * 32 + c] : We1[kg * 32 + (c - 32)];
            }
        }
        if (tid < 128) {
            int nn = tid >> 3, q = tid & 7;
            float4 v = *(const float4*)(feat + (m0 + nn) * 512 + kt * 32 + q * 4);
            FL[nn][q * 4 + 0] = v.x; FL[nn][q * 4 + 1] = v.y;
            FL[nn][q * 4 + 2] = v.z; FL[nn][q * 4 + 3] = v.w;
        }
        __syncthreads();
        #pragma unroll 4
        for (int k = 0; k < 32; k++) {
            float4 w = *(const float4*)&WL[k][cr * 4];
            float f0 = FL[n][k];
            acc[0] += f0 * w.x; acc[1] += f0 * w.y;
            acc[2] += f0 * w.z; acc[3] += f0 * w.w;
        }
    }
    int cg = cr * 4;
    if (cg < 32) {
        float4 v = make_float4(acc[0], acc[1], acc[2], acc[3]);
        *(float4*)(xwg + (m0 + n) * 32 + cg) = v;
    } else {
        int hc = cg - 32;
        #pragma unroll
        for (int t = 0; t < 4; t++) {
            float v = acc[t] + be1[hc + t];
            HE[n][hc + t] = v > 0.f ? v : 0.f;
        }
    }
    __syncthreads();
    {
        int j = cr;
        float s = be2[j];
        #pragma unroll 8
        for (int cc = 0; cc < 32; cc++) s += HE[n][cc] * We2[cc * 16 + j];
        zxf[(m0 + n) * 16 + j] = s > 0.f ? s : 0.f;
    }
}

// ---------------------------------------------------------------------------
// CSR build: histogram, scan
// ---------------------------------------------------------------------------
__global__ __launch_bounds__(256) void k_hist(const int* __restrict__ edst, int* __restrict__ counts) {
    int e = blockIdx.x * 256 + threadIdx.x;
    atomicAdd(&counts[edst[e]], 1);
}

__global__ __launch_bounds__(1024) void k_scan(const int* __restrict__ counts,
                                               int* __restrict__ offs, int* __restrict__ cursor) {
    __shared__ int sdata[1024];
    int t = threadIdx.x;
    int base = t * 8;
    int c[8], local[8];
    int s = 0;
    #pragma unroll
    for (int j = 0; j < 8; j++) { c[j] = counts[base + j]; }
    #pragma unroll
    for (int j = 0; j < 8; j++) { local[j] = s; s += c[j]; }
    sdata[t] = s;
    __syncthreads();
    for (int off = 1; off < 1024; off <<= 1) {
        int v = sdata[t];
        int add = (t >= off) ? sdata[t - off] : 0;
        __syncthreads();
        sdata[t] = v + add;
        __syncthreads();
    }
    int excl = (t == 0) ? 0 : sdata[t - 1];
    #pragma unroll
    for (int j = 0; j < 8; j++) {
        int o = excl + local[j];
        offs[base + j] = o;
        cursor[base + j] = o;
    }
}

// ---------------------------------------------------------------------------
// K_scatfeat: blocks [0,1024): CSR scatter; blocks [1024,1536): feat decoder
// (independent dependency chains — scatter<-scan, feat<-enc).
// ---------------------------------------------------------------------------
__global__ __launch_bounds__(256) void k_scatfeat(const int* __restrict__ esrc,
                                                  const int* __restrict__ edst,
                                                  const float* __restrict__ ew,
                                                  int* __restrict__ cursor,
                                                  int2* __restrict__ sedge,
                                                  const float* __restrict__ zxf,
                                                  const float* __restrict__ Wd1,
                                                  const float* __restrict__ bd1,
                                                  const float* __restrict__ Wd2,
                                                  const float* __restrict__ bd2,
                                                  float* __restrict__ outF) {
    __shared__ float ZL[16][17];
    __shared__ float HT[16][33];
    int tid = threadIdx.x;
    if (blockIdx.x < 1024) {
        int e = blockIdx.x * 256 + tid;
        int d = edst[e];
        int pos = atomicAdd(&cursor[d], 1);
        sedge[pos] = make_int2(esrc[e], __float_as_int(ew[e]));
    } else {
        int m0 = (int)(blockIdx.x - 1024) * 16;
        {
            int n = tid >> 4, k = tid & 15;
            ZL[n][k] = zxf[(m0 + n) * 16 + k];
        }
        __syncthreads();
        {
            int o = tid * 2;
            int n = o >> 5, c = o & 31;
            float s0 = bd1[c], s1 = bd1[c + 1];
            #pragma unroll
            for (int k = 0; k < 16; k++) {
                float z = ZL[n][k];
                s0 += z * Wd1[k * 32 + c];
                s1 += z * Wd1[k * 32 + c + 1];
            }
            HT[n][c] = s0 > 0.f ? s0 : 0.f;
            HT[n][c + 1] = s1 > 0.f ? s1 : 0.f;
        }
        __syncthreads();
        int c2 = tid * 2;
        floatx2 acc[16];
        #pragma unroll
        for (int n = 0; n < 16; n++) acc[n] = (floatx2){0.f, 0.f};
        for (int k = 0; k < 32; k++) {
            float2 w = *(const float2*)(Wd2 + k * 512 + c2);
            #pragma unroll
            for (int n = 0; n < 16; n++) {
                float t = HT[n][k];
                acc[n].x += t * w.x;
                acc[n].y += t * w.y;
            }
        }
        float b0 = bd2[c2], b1 = bd2[c2 + 1];
        #pragma unroll
        for (int n = 0; n < 16; n++) {
            float s0 = acc[n].x + b0, s1 = acc[n].y + b1;
            s0 = s0 > 0.f ? s0 : 0.f;
            s1 = s1 > 0.f ? s1 : 0.f;
            floatx2 pk = {s0, s1};
            *(floatx2*)(outF + (size_t)(m0 + n) * 512 + c2) = pk;
        }
    }
}

// ---------------------------------------------------------------------------
// K_agg1: h = relu(segsum(xwg[src]*w) + bg1); hw2 = h @ Wg2
// ---------------------------------------------------------------------------
__global__ __launch_bounds__(256) void k_agg1(const float* __restrict__ xwg,
                                              const int* __restrict__ offs,
                                              const int* __restrict__ counts,
                                              const int2* __restrict__ sedge,
                                              const float* __restrict__ bg1,
                                              const float* __restrict__ Wg2,
                                              float* __restrict__ hw2) {
    __shared__ float hsh[8][33];
    int ln = threadIdx.x >> 5, c = threadIdx.x & 31;
    int n = blockIdx.x * 8 + ln;
    int st = offs[n], en = st + counts[n];
    float acc = 0.f;
    int i = st;
    for (; i + 4 <= en; i += 4) {
        int2 e0 = sedge[i], e1 = sedge[i + 1], e2 = sedge[i + 2], e3 = sedge[i + 3];
        float s0 = __int_as_float(e0.y) * xwg[e0.x * 32 + c];
        float s1 = __int_as_float(e1.y) * xwg[e1.x * 32 + c];
        float s2 = __int_as_float(e2.y) * xwg[e2.x * 32 + c];
        float s3 = __int_as_float(e3.y) * xwg[e3.x * 32 + c];
        acc += (s0 + s1) + (s2 + s3);
    }
    for (; i < en; i++) {
        int2 e = sedge[i];
        acc += __int_as_float(e.y) * xwg[e.x * 32 + c];
    }
    float h = acc + bg1[c];
    hsh[ln][c] = h > 0.f ? h : 0.f;
    __syncthreads();
    if (threadIdx.x < 128) {
        int l2 = threadIdx.x >> 4, j = threadIdx.x & 15;
        float s2 = 0.f;
        #pragma unroll 8
        for (int cc = 0; cc < 32; cc++) s2 += hsh[l2][cc] * Wg2[cc * 16 + j];
        hw2[(blockIdx.x * 8 + l2) * 16 + j] = s2;
    }
}

// ---------------------------------------------------------------------------
// K_agg2: za = relu(segsum(hw2[src]*w) + bg2); z output (f32) + zbf (bf16)
// ---------------------------------------------------------------------------
__global__ __launch_bounds__(256) void k_agg2(const float* __restrict__ hw2,
                                              const int* __restrict__ offs,
                                              const int* __restrict__ counts,
                                              const int2* __restrict__ sedge,
                                              const float* __restrict__ bg2,
                                              const float* __restrict__ zxf,
                                              ushort_t* __restrict__ zbf,
                                              float* __restrict__ zout) {
    int ln = threadIdx.x >> 4, c = threadIdx.x & 15;
    int n = blockIdx.x * 16 + ln;
    int st = offs[n], en = st + counts[n];
    float acc = 0.f;
    int i = st;
    for (; i + 4 <= en; i += 4) {
        int2 e0 = sedge[i], e1 = sedge[i + 1], e2 = sedge[i + 2], e3 = sedge[i + 3];
        float s0 = __int_as_float(e0.y) * hw2[e0.x * 16 + c];
        float s1 = __int_as_float(e1.y) * hw2[e1.x * 16 + c];
        float s2 = __int_as_float(e2.y) * hw2[e2.x * 16 + c];
        float s3 = __int_as_float(e3.y) * hw2[e3.x * 16 + c];
        acc += (s0 + s1) + (s2 + s3);
    }
    for (; i < en; i++) {
        int2 e = sedge[i];
        acc += __int_as_float(e.y) * hw2[e.x * 16 + c];
    }
    float za = acc + bg2[c];
    za = za > 0.f ? za : 0.f;
    float zx = zxf[n * 16 + c];
    zout[n * 32 + c] = za;
    zout[n * 32 + 16 + c] = zx;
    zbf[n * 32 + c] = f2bf(za);
    zbf[n * 32 + 16 + c] = f2bf(zx);
}

// ---------------------------------------------------------------------------
// K_adj: adj = sigmoid(z z^T) via bf16 MFMA, LDS-transposed epilogue.
// Block = 128 thr (2 waves). Wave owns 16 rows x 512 cols, processed as
// 2 tiles of 16x256. MFMA C-frags -> wave-private LDS (16 KB) -> row-major
// readback: every global store is 1 KB contiguous in ONE row, rows written
// sequentially (single open HBM stream per wave).
// ---------------------------------------------------------------------------
__global__ __launch_bounds__(128) void k_adj(const ushort_t* __restrict__ zbf,
                                             float* __restrict__ adj) {
    __shared__ float TB[2][16][256];   // 32 KB: per-wave 16x256 tile
    int tid = threadIdx.x;
    int l = tid & 63;
    int wv = tid >> 6;                 // 0..1
    int strip = blockIdx.x & 15;
    int rt = (blockIdx.x >> 4) * 2 + wv;
    int q = l >> 4, cl = l & 15;
    int m0 = rt * 16, c0 = strip * 512;
    float (*T)[256] = TB[wv];

    short8 a = *(const short8*)(zbf + (m0 + cl) * 32 + q * 8);
    for (int half = 0; half < 2; half++) {
        int cb0 = c0 + half * 256;
        __syncthreads();               // WAR: previous half's reads done
        #pragma unroll
        for (int g = 0; g < 4; g++) {
            int cb = cb0 + g * 64;
            short8 b0 = *(const short8*)(zbf + (cb + 4 * cl + 0) * 32 + q * 8);
            short8 b1 = *(const short8*)(zbf + (cb + 4 * cl + 1) * 32 + q * 8);
            short8 b2 = *(const short8*)(zbf + (cb + 4 * cl + 2) * 32 + q * 8);
            short8 b3 = *(const short8*)(zbf + (cb + 4 * cl + 3) * 32 + q * 8);
            floatx4 zv = {0, 0, 0, 0};
            floatx4 a0 = __builtin_amdgcn_mfma_f32_16x16x32_bf16(a, b0, zv, 0, 0, 0);
            floatx4 a1 = __builtin_amdgcn_mfma_f32_16x16x32_bf16(a, b1, zv, 0, 0, 0);
            floatx4 a2 = __builtin_amdgcn_mfma_f32_16x16x32_bf16(a, b2, zv, 0, 0, 0);
            floatx4 a3 = __builtin_amdgcn_mfma_f32_16x16x32_bf16(a, b3, zv, 0, 0, 0);
            #pragma unroll
            for (int r = 0; r < 4; r++) {
                floatx4 v;
                v.x = fsig(a0[r]);
                v.y = fsig(a1[r]);
                v.z = fsig(a2[r]);
                v.w = fsig(a3[r]);
                *(floatx4*)&T[q * 4 + r][g * 64 + 4 * cl] = v;
            }
        }
        __syncthreads();               // RAW: all lanes' writes visible
        #pragma unroll 4
        for (int r = 0; r < 16; r++) {
            floatx4 v = *(const floatx4*)&T[r][4 * l];
            __builtin_nontemporal_store(v, (floatx4*)(adj + (size_t)(m0 + r) * 8192 + cb0 + 4 * l));
        }
    }
}

// ---------------------------------------------------------------------------
extern "C" void kernel_launch(void* const* d_in, const int* in_sizes, int n_in,
                              void* d_out, int out_size, void* d_ws, size_t ws_size,
                              hipStream_t stream) {
    const float* feat = (const float*)d_in[0];
    const int* esrc = (const int*)d_in[1];
    const int* edst = (const int*)d_in[2];
    const float* ew = (const float*)d_in[3];
    const float* Wg1 = (const float*)d_in[4];
    const float* bg1 = (const float*)d_in[5];
    const float* Wg2 = (const float*)d_in[6];
    const float* bg2 = (const float*)d_in[7];
    const float* We1 = (const float*)d_in[8];
    const float* be1 = (const float*)d_in[9];
    const float* We2 = (const float*)d_in[10];
    const float* be2 = (const float*)d_in[11];
    const float* Wd1 = (const float*)d_in[12];
    const float* bd1 = (const float*)d_in[13];
    const float* Wd2 = (const float*)d_in[14];
    const float* bd2 = (const float*)d_in[15];
    float* out = (float*)d_out;

    char* ws = (char*)d_ws;
    float* xwg      = (float*)(ws + 0);            // 1 MB
    float* zxf      = (float*)(ws + 1048576);      // 512 KB
    float* hw2      = (float*)(ws + 1572864);      // 512 KB
    ushort_t* zbf   = (ushort_t*)(ws + 2097152);   // 512 KB
    int* counts     = (int*)(ws + 2621440);        // 32 KB
    int* offs       = (int*)(ws + 2654208);        // 32 KB
    int* cursor     = (int*)(ws + 2686976);        // 32 KB
    int2* sedge     = (int2*)(ws + 2719744);       // 2 MB

    k_enc<<<N_NODES / 16, 256, 0, stream>>>(feat, Wg1, We1, be1, We2, be2,
                                            xwg, zxf, counts);
    k_hist<<<N_EDGES / 256, 256, 0, stream>>>(edst, counts);
    k_scan<<<1, 1024, 0, stream>>>(counts, offs, cursor);
    k_scatfeat<<<1024 + 512, 256, 0, stream>>>(esrc, edst, ew, cursor, sedge,
                                               zxf, Wd1, bd1, Wd2, bd2, out + FEAT_OFF);
    k_agg1<<<N_NODES / 8, 256, 0, stream>>>(xwg, offs, counts, sedge, bg1, Wg2, hw2);
    k_agg2<<<N_NODES / 16, 256, 0, stream>>>(hw2, offs, counts, sedge, bg2, zxf,
                                             zbf, out + Z_OFF);
    k_adj<<<(N_NODES / 16 / 2) * 16, 128, 0, stream>>>(zbf, out + ADJ_OFF);
}

// Round 10
// 428.505 us; speedup vs baseline: 1.0439x; 1.0231x over previous
//
#include <hip/hip_runtime.h>

typedef unsigned short ushort_t;
typedef __attribute__((ext_vector_type(8))) short short8;
typedef __attribute__((ext_vector_type(4))) float floatx4;
typedef __attribute__((ext_vector_type(2))) float floatx2;

#define N_NODES 8192
#define N_EDGES 262144
#define D_FEAT 512
#define NHID 32
#define LATENT 16

#define ADJ_OFF 0
#define FEAT_OFF (8192*8192)
#define Z_OFF (8192*8192 + 8192*512)

#define BCAP 128   // bucket capacity per node; deg ~ Poisson(32), P(>=128) ~ 1e-40

static __device__ __forceinline__ ushort_t f2bf(float f) {
    unsigned int u = __float_as_uint(f);
    unsigned int r = u + 0x7fffu + ((u >> 16) & 1u);  // RNE
    return (ushort_t)(r >> 16);
}

// sigmoid via native exp2 + rcp; |err| ~1e-7
static __device__ __forceinline__ float fsig(float x) {
    float e = __builtin_amdgcn_exp2f(x * -1.44269504f);
    return __builtin_amdgcn_rcpf(1.f + e);
}

// ---------------------------------------------------------------------------
// K_enc: xwg = feat @ Wg1 ; he1 = relu(feat @ We1 + be1) ; zx = relu(he1@We2+be2)
// 512 blocks x 16 nodes. Also zeroes cnt[] for the bucket scatter.
// ---------------------------------------------------------------------------
__global__ __launch_bounds__(256) void k_enc(const float* __restrict__ feat,
                                             const float* __restrict__ Wg1,
                                             const float* __restrict__ We1,
                                             const float* __restrict__ be1,
                                             const float* __restrict__ We2,
                                             const float* __restrict__ be2,
                                             float* __restrict__ xwg,
                                             float* __restrict__ zxf,
                                             int* __restrict__ cnt) {
    __shared__ float WL[32][64];
    __shared__ float FL[16][36];
    __shared__ float HE[16][33];
    int tid = threadIdx.x;
    int gid = blockIdx.x * 256 + tid;
    if (gid < N_NODES) cnt[gid] = 0;

    int n = tid >> 4;
    int cr = tid & 15;
    int m0 = blockIdx.x * 16;
    float acc[4] = {};

    for (int kt = 0; kt < 16; kt++) {
        __syncthreads();
        {
            int i = tid;
            #pragma unroll
            for (int j = 0; j < 8; j++, i += 256) {
                int k = i >> 6, c = i & 63;
                int kg = kt * 32 + k;
                WL[k][c] = (c < 32) ? Wg1[kg * 32 + c] : We1[kg * 32 + (c - 32)];
            }
        }
        if (tid < 128) {
            int nn = tid >> 3, q = tid & 7;
            float4 v = *(const float4*)(feat + (m0 + nn) * 512 + kt * 32 + q * 4);
            FL[nn][q * 4 + 0] = v.x; FL[nn][q * 4 + 1] = v.y;
            FL[nn][q * 4 + 2] = v.z; FL[nn][q * 4 + 3] = v.w;
        }
        __syncthreads();
        #pragma unroll 4
        for (int k = 0; k < 32; k++) {
            float4 w = *(const float4*)&WL[k][cr * 4];
            float f0 = FL[n][k];
            acc[0] += f0 * w.x; acc[1] += f0 * w.y;
            acc[2] += f0 * w.z; acc[3] += f0 * w.w;
        }
    }
    int cg = cr * 4;
    if (cg < 32) {
        float4 v = make_float4(acc[0], acc[1], acc[2], acc[3]);
        *(float4*)(xwg + (m0 + n) * 32 + cg) = v;
    } else {
        int hc = cg - 32;
        #pragma unroll
        for (int t = 0; t < 4; t++) {
            float v = acc[t] + be1[hc + t];
            HE[n][hc + t] = v > 0.f ? v : 0.f;
        }
    }
    __syncthreads();
    {
        int j = cr;
        float s = be2[j];
        #pragma unroll 8
        for (int cc = 0; cc < 32; cc++) s += HE[n][cc] * We2[cc * 16 + j];
        zxf[(m0 + n) * 16 + j] = s > 0.f ? s : 0.f;
    }
}

// ---------------------------------------------------------------------------
// K_scatfeat: blocks [0,1024): bucket scatter (count + place in ONE pass —
// no hist/scan dispatches); blocks [1024,1536): feat decoder.
// ---------------------------------------------------------------------------
__global__ __launch_bounds__(256) void k_scatfeat(const int* __restrict__ esrc,
                                                  const int* __restrict__ edst,
                                                  const float* __restrict__ ew,
                                                  int* __restrict__ cnt,
                                                  int2* __restrict__ sedge,
                                                  const float* __restrict__ zxf,
                                                  const float* __restrict__ Wd1,
                                                  const float* __restrict__ bd1,
                                                  const float* __restrict__ Wd2,
                                                  const float* __restrict__ bd2,
                                                  float* __restrict__ outF) {
    __shared__ float ZL[16][17];
    __shared__ float HT[16][33];
    int tid = threadIdx.x;
    if (blockIdx.x < 1024) {
        int e = blockIdx.x * 256 + tid;
        int d = edst[e];
        int pos = atomicAdd(&cnt[d], 1);
        if (pos < BCAP)
            sedge[d * BCAP + pos] = make_int2(esrc[e], __float_as_int(ew[e]));
    } else {
        int m0 = (int)(blockIdx.x - 1024) * 16;
        {
            int n = tid >> 4, k = tid & 15;
            ZL[n][k] = zxf[(m0 + n) * 16 + k];
        }
        __syncthreads();
        {
            int o = tid * 2;
            int n = o >> 5, c = o & 31;
            float s0 = bd1[c], s1 = bd1[c + 1];
            #pragma unroll
            for (int k = 0; k < 16; k++) {
                float z = ZL[n][k];
                s0 += z * Wd1[k * 32 + c];
                s1 += z * Wd1[k * 32 + c + 1];
            }
            HT[n][c] = s0 > 0.f ? s0 : 0.f;
            HT[n][c + 1] = s1 > 0.f ? s1 : 0.f;
        }
        __syncthreads();
        int c2 = tid * 2;
        floatx2 acc[16];
        #pragma unroll
        for (int n = 0; n < 16; n++) acc[n] = (floatx2){0.f, 0.f};
        for (int k = 0; k < 32; k++) {
            float2 w = *(const float2*)(Wd2 + k * 512 + c2);
            #pragma unroll
            for (int n = 0; n < 16; n++) {
                float t = HT[n][k];
                acc[n].x += t * w.x;
                acc[n].y += t * w.y;
            }
        }
        float b0 = bd2[c2], b1 = bd2[c2 + 1];
        #pragma unroll
        for (int n = 0; n < 16; n++) {
            float s0 = acc[n].x + b0, s1 = acc[n].y + b1;
            s0 = s0 > 0.f ? s0 : 0.f;
            s1 = s1 > 0.f ? s1 : 0.f;
            floatx2 pk = {s0, s1};
            *(floatx2*)(outF + (size_t)(m0 + n) * 512 + c2) = pk;
        }
    }
}

// ---------------------------------------------------------------------------
// K_agg1: h = relu(bucketsum(xwg[src]*w) + bg1); hw2 = h @ Wg2
// ---------------------------------------------------------------------------
__global__ __launch_bounds__(256) void k_agg1(const float* __restrict__ xwg,
                                              const int* __restrict__ cnt,
                                              const int2* __restrict__ sedge,
                                              const float* __restrict__ bg1,
                                              const float* __restrict__ Wg2,
                                              float* __restrict__ hw2) {
    __shared__ float hsh[8][33];
    int ln = threadIdx.x >> 5, c = threadIdx.x & 31;
    int n = blockIdx.x * 8 + ln;
    int st = n * BCAP, en = st + min(cnt[n], BCAP);
    float acc = 0.f;
    int i = st;
    for (; i + 4 <= en; i += 4) {
        int2 e0 = sedge[i], e1 = sedge[i + 1], e2 = sedge[i + 2], e3 = sedge[i + 3];
        float s0 = __int_as_float(e0.y) * xwg[e0.x * 32 + c];
        float s1 = __int_as_float(e1.y) * xwg[e1.x * 32 + c];
        float s2 = __int_as_float(e2.y) * xwg[e2.x * 32 + c];
        float s3 = __int_as_float(e3.y) * xwg[e3.x * 32 + c];
        acc += (s0 + s1) + (s2 + s3);
    }
    for (; i < en; i++) {
        int2 e = sedge[i];
        acc += __int_as_float(e.y) * xwg[e.x * 32 + c];
    }
    float h = acc + bg1[c];
    hsh[ln][c] = h > 0.f ? h : 0.f;
    __syncthreads();
    if (threadIdx.x < 128) {
        int l2 = threadIdx.x >> 4, j = threadIdx.x & 15;
        float s2 = 0.f;
        #pragma unroll 8
        for (int cc = 0; cc < 32; cc++) s2 += hsh[l2][cc] * Wg2[cc * 16 + j];
        hw2[(blockIdx.x * 8 + l2) * 16 + j] = s2;
    }
}

// ---------------------------------------------------------------------------
// K_agg2: za = relu(bucketsum(hw2[src]*w) + bg2); z output (f32) + zbf (bf16)
// ---------------------------------------------------------------------------
__global__ __launch_bounds__(256) void k_agg2(const float* __restrict__ hw2,
                                              const int* __restrict__ cnt,
                                              const int2* __restrict__ sedge,
                                              const float* __restrict__ bg2,
                                              const float* __restrict__ zxf,
                                              ushort_t* __restrict__ zbf,
                                              float* __restrict__ zout) {
    int ln = threadIdx.x >> 4, c = threadIdx.x & 15;
    int n = blockIdx.x * 16 + ln;
    int st = n * BCAP, en = st + min(cnt[n], BCAP);
    float acc = 0.f;
    int i = st;
    for (; i + 4 <= en; i += 4) {
        int2 e0 = sedge[i], e1 = sedge[i + 1], e2 = sedge[i + 2], e3 = sedge[i + 3];
        float s0 = __int_as_float(e0.y) * hw2[e0.x * 16 + c];
        float s1 = __int_as_float(e1.y) * hw2[e1.x * 16 + c];
        float s2 = __int_as_float(e2.y) * hw2[e2.x * 16 + c];
        float s3 = __int_as_float(e3.y) * hw2[e3.x * 16 + c];
        acc += (s0 + s1) + (s2 + s3);
    }
    for (; i < en; i++) {
        int2 e = sedge[i];
        acc += __int_as_float(e.y) * hw2[e.x * 16 + c];
    }
    float za = acc + bg2[c];
    za = za > 0.f ? za : 0.f;
    float zx = zxf[n * 16 + c];
    zout[n * 32 + c] = za;
    zout[n * 32 + 16 + c] = zx;
    zbf[n * 32 + c] = f2bf(za);
    zbf[n * 32 + 16 + c] = f2bf(zx);
}

// ---------------------------------------------------------------------------
// K_adj: adj = sigmoid(z z^T) via bf16 MFMA, LDS-transposed epilogue
// (1 KB-contiguous row stores). Block = 128 thr (2 waves), 32 KB LDS.
// ---------------------------------------------------------------------------
__global__ __launch_bounds__(128) void k_adj(const ushort_t* __restrict__ zbf,
                                             float* __restrict__ adj) {
    __shared__ float TB[2][16][256];
    int tid = threadIdx.x;
    int l = tid & 63;
    int wv = tid >> 6;
    int strip = blockIdx.x & 15;
    int rt = (blockIdx.x >> 4) * 2 + wv;
    int q = l >> 4, cl = l & 15;
    int m0 = rt * 16, c0 = strip * 512;
    float (*T)[256] = TB[wv];

    short8 a = *(const short8*)(zbf + (m0 + cl) * 32 + q * 8);
    for (int half = 0; half < 2; half++) {
        int cb0 = c0 + half * 256;
        __syncthreads();
        #pragma unroll
        for (int g = 0; g < 4; g++) {
            int cb = cb0 + g * 64;
            short8 b0 = *(const short8*)(zbf + (cb + 4 * cl + 0) * 32 + q * 8);
            short8 b1 = *(const short8*)(zbf + (cb + 4 * cl + 1) * 32 + q * 8);
            short8 b2 = *(const short8*)(zbf + (cb + 4 * cl + 2) * 32 + q * 8);
            short8 b3 = *(const short8*)(zbf + (cb + 4 * cl + 3) * 32 + q * 8);
            floatx4 zv = {0, 0, 0, 0};
            floatx4 a0 = __builtin_amdgcn_mfma_f32_16x16x32_bf16(a, b0, zv, 0, 0, 0);
            floatx4 a1 = __builtin_amdgcn_mfma_f32_16x16x32_bf16(a, b1, zv, 0, 0, 0);
            floatx4 a2 = __builtin_amdgcn_mfma_f32_16x16x32_bf16(a, b2, zv, 0, 0, 0);
            floatx4 a3 = __builtin_amdgcn_mfma_f32_16x16x32_bf16(a, b3, zv, 0, 0, 0);
            #pragma unroll
            for (int r = 0; r < 4; r++) {
                floatx4 v;
                v.x = fsig(a0[r]);
                v.y = fsig(a1[r]);
                v.z = fsig(a2[r]);
                v.w = fsig(a3[r]);
                *(floatx4*)&T[q * 4 + r][g * 64 + 4 * cl] = v;
            }
        }
        __syncthreads();
        #pragma unroll 4
        for (int r = 0; r < 16; r++) {
            floatx4 v = *(const floatx4*)&T[r][4 * l];
            __builtin_nontemporal_store(v, (floatx4*)(adj + (size_t)(m0 + r) * 8192 + cb0 + 4 * l));
        }
    }
}

// ---------------------------------------------------------------------------
extern "C" void kernel_launch(void* const* d_in, const int* in_sizes, int n_in,
                              void* d_out, int out_size, void* d_ws, size_t ws_size,
                              hipStream_t stream) {
    const float* feat = (const float*)d_in[0];
    const int* esrc = (const int*)d_in[1];
    const int* edst = (const int*)d_in[2];
    const float* ew = (const float*)d_in[3];
    const float* Wg1 = (const float*)d_in[4];
    const float* bg1 = (const float*)d_in[5];
    const float* Wg2 = (const float*)d_in[6];
    const float* bg2 = (const float*)d_in[7];
    const float* We1 = (const float*)d_in[8];
    const float* be1 = (const float*)d_in[9];
    const float* We2 = (const float*)d_in[10];
    const float* be2 = (const float*)d_in[11];
    const float* Wd1 = (const float*)d_in[12];
    const float* bd1 = (const float*)d_in[13];
    const float* Wd2 = (const float*)d_in[14];
    const float* bd2 = (const float*)d_in[15];
    float* out = (float*)d_out;

    char* ws = (char*)d_ws;
    float* xwg      = (float*)(ws + 0);            // 1 MB
    float* zxf      = (float*)(ws + 1048576);      // 512 KB
    float* hw2      = (float*)(ws + 1572864);      // 512 KB
    ushort_t* zbf   = (ushort_t*)(ws + 2097152);   // 512 KB
    int* cnt        = (int*)(ws + 2621440);        // 32 KB
    int2* sedge     = (int2*)(ws + 2654208);       // 8 MB (8192 * 128 * 8 B)

    k_enc<<<N_NODES / 16, 256, 0, stream>>>(feat, Wg1, We1, be1, We2, be2,
                                            xwg, zxf, cnt);
    k_scatfeat<<<1024 + 512, 256, 0, stream>>>(esrc, edst, ew, cnt, sedge,
                                               zxf, Wd1, bd1, Wd2, bd2, out + FEAT_OFF);
    k_agg1<<<N_NODES / 8, 256, 0, stream>>>(xwg, cnt, sedge, bg1, Wg2, hw2);
    k_agg2<<<N_NODES / 16, 256, 0, stream>>>(hw2, cnt, sedge, bg2, zxf,
                                             zbf, out + Z_OFF);
    k_adj<<<(N_NODES / 16 / 2) * 16, 128, 0, stream>>>(zbf, out + ADJ_OFF);
}